// Round 7
// baseline (1344.375 us; speedup 1.0000x reference)
//
#include <hip/hip_runtime.h>

#define BB 128
#define TT 2048
#define KK 64

__device__ __forceinline__ float rlane_f(float v, int lane) {
    return __int_as_float(__builtin_amdgcn_readlane(__float_as_int(v), lane));
}

// 3-way argmax combine, first-occurrence on ties (requires ai<bi<ci ranges)
__device__ __forceinline__ void cmb3(float av, int ai, float bv, int bi,
                                     float cv, int ci, float& ov, int& oi) {
    float m = fmaxf(fmaxf(av, bv), cv);   // folds to v_max3_f32
    int tbc = (bv == m) ? bi : ci;
    oi = (av == m) ? ai : tbc;
    ov = m;
}

__global__ __launch_bounds__(64) __attribute__((amdgpu_waves_per_eu(1, 1)))
void viterbi64(const float* __restrict__ em, const int* __restrict__ mask,
               const float* __restrict__ trans, int* __restrict__ out,
               unsigned char* __restrict__ bp)
{
    const int b = blockIdx.x;
    const int lane = threadIdx.x;
    const float* emb = em + (size_t)b * TT * KK;
    unsigned char* bpb = bp + (size_t)b * TT * KK;
    int* outb = out + (size_t)b * TT;

    // transition column: tcol[i] = trans[i][lane], pinned resident
    float tcol[KK];
#pragma unroll
    for (int i = 0; i < KK; ++i) tcol[i] = trans[i * KK + lane];
#pragma unroll
    for (int i = 0; i < KK; ++i) asm volatile("" : "+v"(tcol[i]));

    // length = index of first zero in prefix mask (or T)
    int len = TT;
#pragma unroll 1
    for (int c = 0; c < TT / 64; ++c) {
        int m = mask[b * TT + c * 64 + lane];
        unsigned long long z = __ballot(m == 0);
        if (z) { len = c * 64 + (__ffsll(z) - 1); break; }
    }
    const int lenm1 = len - 1;

    float score = emb[lane];   // t = 0 init

    // one Viterbi forward step at time tu (1 <= tu <= lenm1)
    // broadcast via readlane (pure reg/VALU loop, no LDS);
    // 8 independent short group-pipelines for ILP, then 8->1 merge
    auto step = [&](float e, int tu) {
        float gv[8]; int gi[8];
#pragma unroll
        for (int g = 0; g < 8; ++g) {
            const int B8 = 8 * g;
            float c0 = rlane_f(score, B8 + 0) + tcol[B8 + 0];
            float c1 = rlane_f(score, B8 + 1) + tcol[B8 + 1];
            float c2 = rlane_f(score, B8 + 2) + tcol[B8 + 2];
            float c3 = rlane_f(score, B8 + 3) + tcol[B8 + 3];
            float c4 = rlane_f(score, B8 + 4) + tcol[B8 + 4];
            float c5 = rlane_f(score, B8 + 5) + tcol[B8 + 5];
            float c6 = rlane_f(score, B8 + 6) + tcol[B8 + 6];
            float c7 = rlane_f(score, B8 + 7) + tcol[B8 + 7];
            float a;  int ai;  cmb3(c0, B8 + 0, c1, B8 + 1, c2, B8 + 2, a, ai);
            float bb_; int bi_; cmb3(c3, B8 + 3, c4, B8 + 4, c5, B8 + 5, bb_, bi_);
            bool tk = c7 > c6;                       // 2-way, left wins ties
            float dv = tk ? c7 : c6;
            int   di = tk ? (B8 + 7) : (B8 + 6);
            cmb3(a, ai, bb_, bi_, dv, di, gv[g], gi[g]);
        }
        float x; int xi; cmb3(gv[0], gi[0], gv[1], gi[1], gv[2], gi[2], x, xi);
        float y; int yi; cmb3(gv[3], gi[3], gv[4], gi[4], gv[5], gi[5], y, yi);
        bool t2 = gv[7] > gv[6];
        float z = t2 ? gv[7] : gv[6];
        int  zi = t2 ? gi[7] : gi[6];
        float best; int bpi; cmb3(x, xi, y, yi, z, zi, best, bpi);

        bpb[(size_t)tu * KK + lane] = (unsigned char)bpi;
        score = best + e;
    };

    // emission prefetch buffer: ebuf[u] holds row (t+u)
    float ebuf[4];
#pragma unroll
    for (int k = 0; k < 4; ++k) {
        int tp = 1 + k; if (tp > TT - 1) tp = TT - 1;
        ebuf[k] = emb[tp * KK + lane];
    }

    int t = 1;
#pragma unroll 1
    for (; t + 3 <= lenm1; t += 4) {
#pragma unroll
        for (int u = 0; u < 4; ++u) {
            float e = ebuf[u];
            int tp = t + 4 + u; if (tp > TT - 1) tp = TT - 1;
            ebuf[u] = emb[tp * KK + lane];       // prefetch 4 ahead
            step(e, t + u);
        }
    }
#pragma unroll 1
    for (; t <= lenm1; ++t) {
        float e = emb[t * KK + lane];
        step(e, t);
    }

    // final argmax over score (first occurrence)
    float bv = score; int bi = lane;
#pragma unroll
    for (int off = 32; off; off >>= 1) {
        float ov = __shfl_xor(bv, off, 64);
        int oi = __shfl_xor(bi, off, 64);
        bool take = (ov > bv) || ((ov == bv) && (oi < bi));
        bv = take ? ov : bv;
        bi = take ? oi : bi;
    }
    int tag = __builtin_amdgcn_readfirstlane(bi);

    // make bp stores visible to our own loads
    asm volatile("s_waitcnt vmcnt(0)" ::: "memory");

    // zero-fill output rows beyond the top backtrack chunk
    const int cbase_top = lenm1 & ~63;
#pragma unroll 1
    for (int t0 = cbase_top + 64; t0 < TT; t0 += 64) outb[t0 + lane] = 0;

    // chunked backtrack: 64 bp rows live in 16 VGPRs (4x uint4)
    // reg q, lane l  <->  row cbase + 16*q + (l>>2), bytes (l&3)*16 .. +15
    const int rsub = lane >> 2;
    const int boff = (lane & 3) * 16;
    uint4 cur[4], nxt[4];
#pragma unroll
    for (int q = 0; q < 4; ++q)
        cur[q] = *(const uint4*)(bpb + (size_t)(cbase_top + 16 * q + rsub) * 64 + boff);
#pragma unroll
    for (int q = 0; q < 4; ++q) nxt[q] = cur[q];

    int stage = 0;   // per-lane staged tags for rows [cbase, cbase+63]
#pragma unroll 1
    for (int cbase = cbase_top; cbase >= 0; cbase -= 64) {
        if (cbase >= 64) {
#pragma unroll
            for (int q = 0; q < 4; ++q)
                nxt[q] = *(const uint4*)(bpb + (size_t)(cbase - 64 + 16 * q + rsub) * 64 + boff);
        }
#pragma unroll
        for (int s = 63; s >= 0; --s) {
            const int row = cbase + s;
            if (row <= lenm1) {                      // uniform branch
                stage = (lane == s) ? tag : stage;   // record tag_row
                if (row >= 1) {                      // tag_{row-1} = bp[row][tag_row]
                    const int q = s >> 4;
                    const int lanei = ((s & 15) << 2) | (tag >> 4);
                    int w0 = __builtin_amdgcn_readlane((int)cur[q].x, lanei);
                    int w1 = __builtin_amdgcn_readlane((int)cur[q].y, lanei);
                    int w2 = __builtin_amdgcn_readlane((int)cur[q].z, lanei);
                    int w3 = __builtin_amdgcn_readlane((int)cur[q].w, lanei);
                    int a0 = (tag & 4) ? w1 : w0;
                    int a1 = (tag & 4) ? w3 : w2;
                    int word = (tag & 8) ? a1 : a0;
                    tag = (word >> ((tag & 3) * 8)) & 0xFF;
                }
            }
        }
        outb[cbase + lane] = stage;
        stage = 0;
#pragma unroll
        for (int q = 0; q < 4; ++q) cur[q] = nxt[q];
    }
}

extern "C" void kernel_launch(void* const* d_in, const int* in_sizes, int n_in,
                              void* d_out, int out_size, void* d_ws, size_t ws_size,
                              hipStream_t stream)
{
    const float* em    = (const float*)d_in[0];
    const int*   mask  = (const int*)d_in[1];
    const float* trans = (const float*)d_in[2];
    int* out = (int*)d_out;
    unsigned char* bp = (unsigned char*)d_ws;   // needs B*T*K = 16 MiB
    viterbi64<<<dim3(BB), dim3(64), 0, stream>>>(em, mask, trans, out, bp);
}

// Round 8
// 881.132 us; speedup vs baseline: 1.5257x; 1.5257x over previous
//
#include <hip/hip_runtime.h>

#define BB 128
#define TT 2048
#define KK 64
#define K2S 32   // k2: t-slice blocks per batch
#define K2W 4    // k2: waves per block

__device__ __forceinline__ float max3f(float a, float b, float c) {
    return fmaxf(fmaxf(a, b), c);   // folds to v_max3_f32
}

__device__ __forceinline__ int find_len(const int* mask, int b, int lane) {
    int len = TT;
#pragma unroll 1
    for (int c = 0; c < TT / 64; ++c) {
        int m = mask[b * TT + c * 64 + lane];
        unsigned long long z = __ballot(m == 0);
        if (z) { len = c * 64 + (__ffsll(z) - 1); break; }
    }
    return len;
}

// ---------- k1: serial forward, max-only, stores score vectors ----------
__global__ __launch_bounds__(64) __attribute__((amdgpu_waves_per_eu(1, 1)))
void vit_fwd(const float* __restrict__ em, const int* __restrict__ mask,
             const float* __restrict__ trans, float* __restrict__ sarr)
{
    __shared__ __align__(16) float sv[KK];
    const int b = blockIdx.x;
    const int lane = threadIdx.x;
    const float* emb = em + (size_t)b * TT * KK;
    float* sb = sarr + (size_t)b * TT * KK;

    float tcol[KK];
#pragma unroll
    for (int i = 0; i < KK; ++i) tcol[i] = trans[i * KK + lane];
#pragma unroll
    for (int i = 0; i < KK; ++i) asm volatile("" : "+v"(tcol[i]));

    const int lenm1 = find_len(mask, b, lane) - 1;

    float score = emb[lane];   // t = 0
    sb[lane] = score;
    sv[lane] = score;

    // one forward step: score_j = max_i(s[i]+T[i][j]) + e_j  (no argmax!)
    auto step = [&](float e, int tu) {
        const float4* svq = (const float4*)sv;
        float c[KK];
#pragma unroll
        for (int g = 0; g < 16; ++g) {
            float4 s4 = svq[g];                  // LDS broadcast read
            c[4*g+0] = s4.x + tcol[4*g+0];
            c[4*g+1] = s4.y + tcol[4*g+1];
            c[4*g+2] = s4.z + tcol[4*g+2];
            c[4*g+3] = s4.w + tcol[4*g+3];
        }
        float m1[22];
#pragma unroll
        for (int g = 0; g < 21; ++g) m1[g] = max3f(c[3*g], c[3*g+1], c[3*g+2]);
        m1[21] = c[63];
        float m2[8];
#pragma unroll
        for (int g = 0; g < 7; ++g) m2[g] = max3f(m1[3*g], m1[3*g+1], m1[3*g+2]);
        m2[7] = m1[21];
        float m3a = max3f(m2[0], m2[1], m2[2]);
        float m3b = max3f(m2[3], m2[4], m2[5]);
        float m3c = fmaxf(m2[6], m2[7]);
        float best = max3f(m3a, m3b, m3c);
        score = best + e;
        sv[lane] = score;                        // publish for next step
        sb[(size_t)tu * KK + lane] = score;      // materialize for k2/k3
    };

    float ebuf[4];
#pragma unroll
    for (int k = 0; k < 4; ++k) {
        int tp = 1 + k; if (tp > TT - 1) tp = TT - 1;
        ebuf[k] = emb[tp * KK + lane];
    }

    int t = 1;
#pragma unroll 1
    for (; t + 3 <= lenm1; t += 4) {
#pragma unroll
        for (int u = 0; u < 4; ++u) {
            float e = ebuf[u];
            int tp = t + 4 + u; if (tp > TT - 1) tp = TT - 1;
            ebuf[u] = emb[tp * KK + lane];       // prefetch 4 ahead
            step(e, t + u);
        }
    }
#pragma unroll 1
    for (; t <= lenm1; ++t) {
        float e = emb[t * KK + lane];
        step(e, t);
    }
}

// ---------- k2: parallel bp recompute from stored score vectors ----------
__global__ __launch_bounds__(64 * K2W)
void vit_bp(const float* __restrict__ sarr, const float* __restrict__ trans,
            unsigned char* __restrict__ bp)
{
    __shared__ __align__(16) float sv[K2W][KK];
    const int b = blockIdx.x / K2S;
    const int sl = blockIdx.x % K2S;
    const int wave = threadIdx.x >> 6;
    const int lane = threadIdx.x & 63;
    const float* sb = sarr + (size_t)b * TT * KK;
    unsigned char* bpb = bp + (size_t)b * TT * KK;

    float tcol[KK];
#pragma unroll
    for (int i = 0; i < KK; ++i) tcol[i] = trans[i * KK + lane];
#pragma unroll
    for (int i = 0; i < KK; ++i) asm volatile("" : "+v"(tcol[i]));

    const int widx = sl * K2W + wave;            // 0..127
    float* svw = sv[wave];
    const float4* svq = (const float4*)svw;

#pragma unroll 1
    for (int t = 1 + widx; t < TT; t += K2S * K2W) {
        svw[lane] = sb[(size_t)(t - 1) * KK + lane];  // wave-private row
        float best; int bpi;
        {
            float4 q = svq[0];
            best = q.x + tcol[0]; bpi = 0;
            float c1 = q.y + tcol[1]; bool k1_ = c1 > best; best = k1_ ? c1 : best; bpi = k1_ ? 1 : bpi;
            float c2 = q.z + tcol[2]; bool k2_ = c2 > best; best = k2_ ? c2 : best; bpi = k2_ ? 2 : bpi;
            float c3 = q.w + tcol[3]; bool k3_ = c3 > best; best = k3_ ? c3 : best; bpi = k3_ ? 3 : bpi;
        }
#pragma unroll
        for (int g = 1; g < 16; ++g) {
            float4 q = svq[g];
            float c0 = q.x + tcol[4*g+0]; bool k0 = c0 > best; best = k0 ? c0 : best; bpi = k0 ? 4*g+0 : bpi;
            float c1 = q.y + tcol[4*g+1]; bool k1_ = c1 > best; best = k1_ ? c1 : best; bpi = k1_ ? 4*g+1 : bpi;
            float c2 = q.z + tcol[4*g+2]; bool k2_ = c2 > best; best = k2_ ? c2 : best; bpi = k2_ ? 4*g+2 : bpi;
            float c3 = q.w + tcol[4*g+3]; bool k3_ = c3 > best; best = k3_ ? c3 : best; bpi = k3_ ? 4*g+3 : bpi;
        }
        bpb[(size_t)t * KK + lane] = (unsigned char)bpi;
    }
}

// ---------- k3: final argmax + chunked backtrack + output ----------
__global__ __launch_bounds__(64)
void vit_bt(const float* __restrict__ sarr, const int* __restrict__ mask,
            const unsigned char* __restrict__ bp, int* __restrict__ out)
{
    const int b = blockIdx.x;
    const int lane = threadIdx.x;
    const float* sb = sarr + (size_t)b * TT * KK;
    const unsigned char* bpb = bp + (size_t)b * TT * KK;
    int* outb = out + (size_t)b * TT;

    const int lenm1 = find_len(mask, b, lane) - 1;

    // final argmax over s[lenm1] (first occurrence)
    float bv = sb[(size_t)lenm1 * KK + lane];
    int bi = lane;
#pragma unroll
    for (int off = 32; off; off >>= 1) {
        float ov = __shfl_xor(bv, off, 64);
        int oi = __shfl_xor(bi, off, 64);
        bool take = (ov > bv) || ((ov == bv) && (oi < bi));
        bv = take ? ov : bv;
        bi = take ? oi : bi;
    }
    int tag = __builtin_amdgcn_readfirstlane(bi);

    // zero-fill output rows beyond the top backtrack chunk
    const int cbase_top = lenm1 & ~63;
#pragma unroll 1
    for (int t0 = cbase_top + 64; t0 < TT; t0 += 64) outb[t0 + lane] = 0;

    // chunked backtrack: 64 bp rows live in 16 VGPRs (4x uint4)
    const int rsub = lane >> 2;
    const int boff = (lane & 3) * 16;
    uint4 cur[4], nxt[4];
#pragma unroll
    for (int q = 0; q < 4; ++q)
        cur[q] = *(const uint4*)(bpb + (size_t)(cbase_top + 16 * q + rsub) * 64 + boff);
#pragma unroll
    for (int q = 0; q < 4; ++q) nxt[q] = cur[q];

    int stage = 0;
#pragma unroll 1
    for (int cbase = cbase_top; cbase >= 0; cbase -= 64) {
        if (cbase >= 64) {
#pragma unroll
            for (int q = 0; q < 4; ++q)
                nxt[q] = *(const uint4*)(bpb + (size_t)(cbase - 64 + 16 * q + rsub) * 64 + boff);
        }
#pragma unroll
        for (int s = 63; s >= 0; --s) {
            const int row = cbase + s;
            if (row <= lenm1) {
                stage = (lane == s) ? tag : stage;
                if (row >= 1) {
                    const int q = s >> 4;
                    const int lanei = ((s & 15) << 2) | (tag >> 4);
                    int w0 = __builtin_amdgcn_readlane((int)cur[q].x, lanei);
                    int w1 = __builtin_amdgcn_readlane((int)cur[q].y, lanei);
                    int w2 = __builtin_amdgcn_readlane((int)cur[q].z, lanei);
                    int w3 = __builtin_amdgcn_readlane((int)cur[q].w, lanei);
                    int a0 = (tag & 4) ? w1 : w0;
                    int a1 = (tag & 4) ? w3 : w2;
                    int word = (tag & 8) ? a1 : a0;
                    tag = (word >> ((tag & 3) * 8)) & 0xFF;
                }
            }
        }
        outb[cbase + lane] = stage;
        stage = 0;
#pragma unroll
        for (int q = 0; q < 4; ++q) cur[q] = nxt[q];
    }
}

// ---------- fallback (R7 monolith) if ws is too small ----------
__device__ __forceinline__ float rlane_f(float v, int lane) {
    return __int_as_float(__builtin_amdgcn_readlane(__float_as_int(v), lane));
}
__device__ __forceinline__ void cmb3(float av, int ai, float bv, int bi,
                                     float cv, int ci, float& ov, int& oi) {
    float m = fmaxf(fmaxf(av, bv), cv);
    int tbc = (bv == m) ? bi : ci;
    oi = (av == m) ? ai : tbc;
    ov = m;
}

__global__ __launch_bounds__(64) __attribute__((amdgpu_waves_per_eu(1, 1)))
void viterbi64(const float* __restrict__ em, const int* __restrict__ mask,
               const float* __restrict__ trans, int* __restrict__ out,
               unsigned char* __restrict__ bp)
{
    const int b = blockIdx.x;
    const int lane = threadIdx.x;
    const float* emb = em + (size_t)b * TT * KK;
    unsigned char* bpb = bp + (size_t)b * TT * KK;
    int* outb = out + (size_t)b * TT;

    float tcol[KK];
#pragma unroll
    for (int i = 0; i < KK; ++i) tcol[i] = trans[i * KK + lane];
#pragma unroll
    for (int i = 0; i < KK; ++i) asm volatile("" : "+v"(tcol[i]));

    const int lenm1 = find_len(mask, b, lane) - 1;
    float score = emb[lane];

    auto step = [&](float e, int tu) {
        float gv[8]; int gi[8];
#pragma unroll
        for (int g = 0; g < 8; ++g) {
            const int B8 = 8 * g;
            float c0 = rlane_f(score, B8 + 0) + tcol[B8 + 0];
            float c1 = rlane_f(score, B8 + 1) + tcol[B8 + 1];
            float c2 = rlane_f(score, B8 + 2) + tcol[B8 + 2];
            float c3 = rlane_f(score, B8 + 3) + tcol[B8 + 3];
            float c4 = rlane_f(score, B8 + 4) + tcol[B8 + 4];
            float c5 = rlane_f(score, B8 + 5) + tcol[B8 + 5];
            float c6 = rlane_f(score, B8 + 6) + tcol[B8 + 6];
            float c7 = rlane_f(score, B8 + 7) + tcol[B8 + 7];
            float a;  int ai;  cmb3(c0, B8 + 0, c1, B8 + 1, c2, B8 + 2, a, ai);
            float bb_; int bi_; cmb3(c3, B8 + 3, c4, B8 + 4, c5, B8 + 5, bb_, bi_);
            bool tk = c7 > c6;
            float dv = tk ? c7 : c6;
            int   di = tk ? (B8 + 7) : (B8 + 6);
            cmb3(a, ai, bb_, bi_, dv, di, gv[g], gi[g]);
        }
        float x; int xi; cmb3(gv[0], gi[0], gv[1], gi[1], gv[2], gi[2], x, xi);
        float y; int yi; cmb3(gv[3], gi[3], gv[4], gi[4], gv[5], gi[5], y, yi);
        bool t2 = gv[7] > gv[6];
        float z = t2 ? gv[7] : gv[6];
        int  zi = t2 ? gi[7] : gi[6];
        float best; int bpi; cmb3(x, xi, y, yi, z, zi, best, bpi);
        bpb[(size_t)tu * KK + lane] = (unsigned char)bpi;
        score = best + e;
    };

    float ebuf[4];
#pragma unroll
    for (int k = 0; k < 4; ++k) {
        int tp = 1 + k; if (tp > TT - 1) tp = TT - 1;
        ebuf[k] = emb[tp * KK + lane];
    }
    int t = 1;
#pragma unroll 1
    for (; t + 3 <= lenm1; t += 4) {
#pragma unroll
        for (int u = 0; u < 4; ++u) {
            float e = ebuf[u];
            int tp = t + 4 + u; if (tp > TT - 1) tp = TT - 1;
            ebuf[u] = emb[tp * KK + lane];
            step(e, t + u);
        }
    }
#pragma unroll 1
    for (; t <= lenm1; ++t) { float e = emb[t * KK + lane]; step(e, t); }

    float bv = score; int bi = lane;
#pragma unroll
    for (int off = 32; off; off >>= 1) {
        float ov = __shfl_xor(bv, off, 64);
        int oi = __shfl_xor(bi, off, 64);
        bool take = (ov > bv) || ((ov == bv) && (oi < bi));
        bv = take ? ov : bv;
        bi = take ? oi : bi;
    }
    int tag = __builtin_amdgcn_readfirstlane(bi);
    asm volatile("s_waitcnt vmcnt(0)" ::: "memory");

    const int cbase_top = lenm1 & ~63;
#pragma unroll 1
    for (int t0 = cbase_top + 64; t0 < TT; t0 += 64) outb[t0 + lane] = 0;

    const int rsub = lane >> 2;
    const int boff = (lane & 3) * 16;
    uint4 cur[4], nxt[4];
#pragma unroll
    for (int q = 0; q < 4; ++q)
        cur[q] = *(const uint4*)(bpb + (size_t)(cbase_top + 16 * q + rsub) * 64 + boff);
#pragma unroll
    for (int q = 0; q < 4; ++q) nxt[q] = cur[q];

    int stage = 0;
#pragma unroll 1
    for (int cbase = cbase_top; cbase >= 0; cbase -= 64) {
        if (cbase >= 64) {
#pragma unroll
            for (int q = 0; q < 4; ++q)
                nxt[q] = *(const uint4*)(bpb + (size_t)(cbase - 64 + 16 * q + rsub) * 64 + boff);
        }
#pragma unroll
        for (int s = 63; s >= 0; --s) {
            const int row = cbase + s;
            if (row <= lenm1) {
                stage = (lane == s) ? tag : stage;
                if (row >= 1) {
                    const int q = s >> 4;
                    const int lanei = ((s & 15) << 2) | (tag >> 4);
                    int w0 = __builtin_amdgcn_readlane((int)cur[q].x, lanei);
                    int w1 = __builtin_amdgcn_readlane((int)cur[q].y, lanei);
                    int w2 = __builtin_amdgcn_readlane((int)cur[q].z, lanei);
                    int w3 = __builtin_amdgcn_readlane((int)cur[q].w, lanei);
                    int a0 = (tag & 4) ? w1 : w0;
                    int a1 = (tag & 4) ? w3 : w2;
                    int word = (tag & 8) ? a1 : a0;
                    tag = (word >> ((tag & 3) * 8)) & 0xFF;
                }
            }
        }
        outb[cbase + lane] = stage;
        stage = 0;
#pragma unroll
        for (int q = 0; q < 4; ++q) cur[q] = nxt[q];
    }
}

extern "C" void kernel_launch(void* const* d_in, const int* in_sizes, int n_in,
                              void* d_out, int out_size, void* d_ws, size_t ws_size,
                              hipStream_t stream)
{
    const float* em    = (const float*)d_in[0];
    const int*   mask  = (const int*)d_in[1];
    const float* trans = (const float*)d_in[2];
    int* out = (int*)d_out;

    const size_t sbytes  = (size_t)BB * TT * KK * sizeof(float);  // 64 MiB
    const size_t bpbytes = (size_t)BB * TT * KK;                  // 16 MiB

    if (ws_size >= sbytes + bpbytes) {
        float* sarr = (float*)d_ws;
        unsigned char* bp = (unsigned char*)d_ws + sbytes;
        vit_fwd<<<dim3(BB), dim3(64), 0, stream>>>(em, mask, trans, sarr);
        vit_bp<<<dim3(BB * K2S), dim3(64 * K2W), 0, stream>>>(sarr, trans, bp);
        vit_bt<<<dim3(BB), dim3(64), 0, stream>>>(sarr, mask, bp, out);
    } else {
        viterbi64<<<dim3(BB), dim3(64), 0, stream>>>(em, mask, trans, out,
                                                     (unsigned char*)d_ws);
    }
}